// Round 1
// baseline (604.493 us; speedup 1.0000x reference)
//
#include <hip/hip_runtime.h>
#include <hip/hip_bf16.h>

// Problem constants
#define BB 64
#define SS 2048
#define DD 512
#define MM (BB * SS)  // 131072 rows

typedef __attribute__((ext_vector_type(8))) short bf16x8;
typedef __attribute__((ext_vector_type(4))) float f32x4;

// fp32 -> bf16 bits, round-to-nearest-even
__device__ __forceinline__ unsigned f2bf(float f) {
    unsigned u = __float_as_uint(f);
    u += 0x7FFFu + ((u >> 16) & 1u);
    return u >> 16;
}

__device__ __forceinline__ float fast_tanh(float x) {
    float ax = fabsf(x);
    float e = __expf(-2.0f * ax);                       // (0,1], never overflows
    float t = (1.0f - e) * __builtin_amdgcn_rcpf(1.0f + e);
    return x < 0.0f ? -t : t;
}

// ---------------------------------------------------------------------------
// Prep 1: W_enc^T cast to bf16:  Bt[n][k] = bf16(W_t[512+k][n]),  n,k in [0,512)
__global__ void prep_w(const float* __restrict__ W, short* __restrict__ Bt) {
    int idx = blockIdx.x * 256 + threadIdx.x;   // 262144 total
    int n = idx >> 9;
    int k = idx & 511;
    Bt[idx] = (short)f2bf(W[(size_t)(512 + k) * DD + n]);
}

// Prep 2: p[b][d] = sum_e dec[b][e] * W_t[e][d] + b_t[d]   (fp32, exact)
__global__ void prep_p(const float* __restrict__ dec, const float* __restrict__ W,
                       const float* __restrict__ bt, float* __restrict__ p) {
    int b = blockIdx.x;
    int d = blockIdx.y * 256 + threadIdx.x;
    float acc = bt[d];
    const float* dv = dec + (size_t)b * DD;
    #pragma unroll 8
    for (int e = 0; e < DD; ++e)
        acc += dv[e] * W[(size_t)e * DD + d];
    p[(size_t)b * DD + d] = acc;
}

// ---------------------------------------------------------------------------
// Score GEMM: score[m] = sum_n tanh(p[b][n] + sum_k enc[m][k]*Wenc[k][n]) * v[n] + b_v
// BM=64 rows/block, BN=512 (full N), BK=32. 256 threads = 4 waves.
// Wave w covers n in [w*128, w*128+128): 4 m-frags x 8 n-frags of 16x16x32 MFMA.
__launch_bounds__(256)
__global__ void score_gemm(const float* __restrict__ enc,
                           const short* __restrict__ Bt,   // bf16 bits [512][512] (n-major)
                           const float* __restrict__ p,    // [64][512]
                           const float* __restrict__ va,   // [512]
                           const float* __restrict__ bv,   // [1]
                           float* __restrict__ score) {    // [131072]
    __shared__ short Alds[64 * 32];    // 4 KB  [row][k]
    __shared__ short Blds[512 * 32];   // 32 KB [n][k]
    __shared__ float sp[4][64];        // per-wave row partials

    const int tid  = threadIdx.x;
    const int wave = tid >> 6;
    const int lane = tid & 63;
    const int m0   = blockIdx.x * 64;

    f32x4 acc[4][8];
    #pragma unroll
    for (int i = 0; i < 4; ++i)
        #pragma unroll
        for (int j = 0; j < 8; ++j)
            acc[i][j] = (f32x4){0.f, 0.f, 0.f, 0.f};

    // A staging: thread t loads row t/4, 8 floats at offset (t%4)*8
    const int arow = tid >> 2;
    const int acol = (tid & 3) * 8;
    const float* aptr = enc + (size_t)(m0 + arow) * DD + acol;

    // B staging via global_load_lds: wave w loads n-rows [w*128, w*128+128),
    // 8 issues of 16 rows (1 KB each); lane l -> row +l/4, 16B chunk (l%4)
    const int brow0 = wave * 128 + (lane >> 2);
    const int bcoff = (lane & 3) * 8;
    const short* bptr = Bt + (size_t)brow0 * DD + bcoff;

    const int lm = lane & 15;
    const int lq = lane >> 4;

    for (int kt = 0; kt < 16; ++kt) {
        const int k0 = kt * 32;
        __syncthreads();
        // ---- stage A (fp32 -> bf16 through VGPRs)
        f32x4 a0 = *(const f32x4*)(aptr + k0);
        f32x4 a1 = *(const f32x4*)(aptr + k0 + 4);
        int4 pk;
        pk.x = f2bf(a0.x) | (f2bf(a0.y) << 16);
        pk.y = f2bf(a0.z) | (f2bf(a0.w) << 16);
        pk.z = f2bf(a1.x) | (f2bf(a1.y) << 16);
        pk.w = f2bf(a1.z) | (f2bf(a1.w) << 16);
        *(int4*)(&Alds[arow * 32 + acol]) = pk;
        // ---- stage B (bf16, direct to LDS)
        #pragma unroll
        for (int i = 0; i < 8; ++i) {
            __builtin_amdgcn_global_load_lds(
                (const __attribute__((address_space(1))) void*)(bptr + (size_t)i * 16 * DD + k0),
                (__attribute__((address_space(3))) void*)(&Blds[(wave * 128 + i * 16) * 32]),
                16, 0, 0);
        }
        __syncthreads();
        // ---- fragments + MFMA
        bf16x8 af[4];
        #pragma unroll
        for (int mf = 0; mf < 4; ++mf)
            af[mf] = *(const bf16x8*)(&Alds[(mf * 16 + lm) * 32 + lq * 8]);
        #pragma unroll
        for (int nf = 0; nf < 8; ++nf) {
            bf16x8 bfr = *(const bf16x8*)(&Blds[(wave * 128 + nf * 16 + lm) * 32 + lq * 8]);
            #pragma unroll
            for (int mf = 0; mf < 4; ++mf)
                acc[mf][nf] = __builtin_amdgcn_mfma_f32_16x16x32_bf16(af[mf], bfr, acc[mf][nf], 0, 0, 0);
        }
    }

    // ---- epilogue: tanh + dot with v, reduce over n
    const int b = m0 >> 11;  // m0 / 2048
    float rowsum[4][4];
    #pragma unroll
    for (int mf = 0; mf < 4; ++mf)
        #pragma unroll
        for (int r = 0; r < 4; ++r) rowsum[mf][r] = 0.f;

    #pragma unroll
    for (int nf = 0; nf < 8; ++nf) {
        int n = wave * 128 + nf * 16 + lm;
        float pv = p[(size_t)b * DD + n];
        float vv = va[n];
        #pragma unroll
        for (int mf = 0; mf < 4; ++mf)
            #pragma unroll
            for (int r = 0; r < 4; ++r)
                rowsum[mf][r] += fast_tanh(pv + acc[mf][nf][r]) * vv;
    }
    // reduce across the 16 lanes holding the same row (cols 0..15 of frag)
    #pragma unroll
    for (int mf = 0; mf < 4; ++mf)
        #pragma unroll
        for (int r = 0; r < 4; ++r) {
            float s = rowsum[mf][r];
            s += __shfl_xor(s, 1);
            s += __shfl_xor(s, 2);
            s += __shfl_xor(s, 4);
            s += __shfl_xor(s, 8);
            rowsum[mf][r] = s;
        }
    if (lm == 0) {
        #pragma unroll
        for (int mf = 0; mf < 4; ++mf)
            #pragma unroll
            for (int r = 0; r < 4; ++r)
                sp[wave][mf * 16 + lq * 4 + r] = rowsum[mf][r];
    }
    __syncthreads();
    if (tid < 64) {
        float sc = sp[0][tid] + sp[1][tid] + sp[2][tid] + sp[3][tid] + bv[0];
        score[(size_t)m0 + tid] = sc;
    }
}

// ---------------------------------------------------------------------------
// Softmax over S per batch; writes alignment (output 1)
__global__ void softmax_k(const float* __restrict__ score, float* __restrict__ align) {
    __shared__ float red[256];
    int b = blockIdx.x, tid = threadIdx.x;
    const float* s = score + (size_t)b * SS;
    float vals[8];
    float mx = -1e30f;
    #pragma unroll
    for (int i = 0; i < 8; ++i) {
        vals[i] = s[i * 256 + tid];
        mx = fmaxf(mx, vals[i]);
    }
    red[tid] = mx; __syncthreads();
    for (int off = 128; off > 0; off >>= 1) {
        if (tid < off) red[tid] = fmaxf(red[tid], red[tid + off]);
        __syncthreads();
    }
    mx = red[0]; __syncthreads();
    float sum = 0.f;
    #pragma unroll
    for (int i = 0; i < 8; ++i) {
        vals[i] = __expf(vals[i] - mx);
        sum += vals[i];
    }
    red[tid] = sum; __syncthreads();
    for (int off = 128; off > 0; off >>= 1) {
        if (tid < off) red[tid] += red[tid + off];
        __syncthreads();
    }
    float inv = 1.0f / red[0];
    #pragma unroll
    for (int i = 0; i < 8; ++i)
        align[(size_t)b * SS + i * 256 + tid] = vals[i] * inv;
}

// ---------------------------------------------------------------------------
// context[b][d] = sum_s align[b][s] * enc[b][s][d]   (atomic accumulate)
__global__ void context_k(const float* __restrict__ enc, const float* __restrict__ align,
                          float* __restrict__ ctx) {
    int bx = blockIdx.x;           // 64 * 16
    int b = bx >> 4, chunk = bx & 15;
    int tid = threadIdx.x;         // 256 threads, float2 each => 512 cols
    const float2* e2 = (const float2*)(enc + ((size_t)b * SS + chunk * 128) * DD);
    const float* a = align + (size_t)b * SS + chunk * 128;
    float2 acc = {0.f, 0.f};
    #pragma unroll 4
    for (int s = 0; s < 128; ++s) {
        float av = a[s];
        float2 e = e2[(size_t)s * 256 + tid];
        acc.x += av * e.x;
        acc.y += av * e.y;
    }
    atomicAdd(&ctx[(size_t)b * DD + tid * 2], acc.x);
    atomicAdd(&ctx[(size_t)b * DD + tid * 2 + 1], acc.y);
}

// ---------------------------------------------------------------------------
extern "C" void kernel_launch(void* const* d_in, const int* in_sizes, int n_in,
                              void* d_out, int out_size, void* d_ws, size_t ws_size,
                              hipStream_t stream) {
    const float* dec = (const float*)d_in[0];  // [64,1,512]
    const float* enc = (const float*)d_in[1];  // [64,2048,512]
    const float* W   = (const float*)d_in[2];  // [1024,512]
    const float* bt  = (const float*)d_in[3];  // [512]
    const float* va  = (const float*)d_in[4];  // [512,1]
    const float* bv  = (const float*)d_in[5];  // [1]

    float* out   = (float*)d_out;
    float* ctx   = out;                 // 32768 floats (output 0)
    float* align = out + BB * DD;       // 131072 floats (output 1)

    char*  ws    = (char*)d_ws;
    short* Bt    = (short*)ws;                                   // 512 KB bf16 W_enc^T
    float* p     = (float*)(ws + 512 * 512 * 2);                 // 128 KB
    float* score = (float*)(ws + 512 * 512 * 2 + BB * DD * 4);   // 512 KB

    hipMemsetAsync(ctx, 0, BB * DD * sizeof(float), stream);
    prep_w<<<1024, 256, 0, stream>>>(W, Bt);
    prep_p<<<dim3(BB, 2), 256, 0, stream>>>(dec, W, bt, p);
    score_gemm<<<MM / 64, 256, 0, stream>>>(enc, Bt, p, va, bv, score);
    softmax_k<<<BB, 256, 0, stream>>>(score, align);
    context_k<<<BB * 16, 256, 0, stream>>>(enc, align, ctx);
}

// Round 2
// 593.819 us; speedup vs baseline: 1.0180x; 1.0180x over previous
//
#include <hip/hip_runtime.h>
#include <hip/hip_bf16.h>

// Problem constants
#define BB 64
#define SS 2048
#define DD 512
#define MM (BB * SS)  // 131072 rows

typedef __attribute__((ext_vector_type(8))) short bf16x8;
typedef __attribute__((ext_vector_type(4))) float f32x4;

// fp32 -> bf16 bits, round-to-nearest-even
__device__ __forceinline__ unsigned f2bf(float f) {
    unsigned u = __float_as_uint(f);
    u += 0x7FFFu + ((u >> 16) & 1u);
    return u >> 16;
}

__device__ __forceinline__ float fast_tanh(float x) {
    float ax = fabsf(x);
    float e = __expf(-2.0f * ax);                       // (0,1], never overflows
    float t = (1.0f - e) * __builtin_amdgcn_rcpf(1.0f + e);
    return x < 0.0f ? -t : t;
}

// ---------------------------------------------------------------------------
// Prep 1: Bt[n][k] = bf16(W_t[512+k][n]).  64x64 LDS tile transpose, both
// global accesses coalesced.
__global__ void prep_w(const float* __restrict__ W, short* __restrict__ Bt) {
    __shared__ float tile[64][65];
    int kt = blockIdx.x >> 3;      // 8 x 8 tiles
    int nt = blockIdx.x & 7;
    int t = threadIdx.x;
    int c = t & 63;
    int rbase = (t >> 6) * 16;
    #pragma unroll
    for (int i = 0; i < 16; ++i) {
        int r = rbase + i;
        tile[r][c] = W[(size_t)(512 + kt * 64 + r) * DD + nt * 64 + c];
    }
    __syncthreads();
    #pragma unroll
    for (int i = 0; i < 16; ++i) {
        int r = rbase + i;
        Bt[(size_t)(nt * 64 + r) * DD + kt * 64 + c] = (short)f2bf(tile[c][r]);
    }
}

// Prep 2: p[b][d] = sum_e dec[b][e] * W_t[e][d] + b_t[d]   (fp32, exact)
__global__ void prep_p(const float* __restrict__ dec, const float* __restrict__ W,
                       const float* __restrict__ bt, float* __restrict__ p) {
    int b = blockIdx.x;
    int d = blockIdx.y * 256 + threadIdx.x;
    float acc = bt[d];
    const float* dv = dec + (size_t)b * DD;
    #pragma unroll 8
    for (int e = 0; e < DD; ++e)
        acc += dv[e] * W[(size_t)e * DD + d];
    p[(size_t)b * DD + d] = acc;
}

// ---------------------------------------------------------------------------
// Score GEMM, n-split partial version:
//   score[m] += sum_{n in slice} tanh(p[b][n] + sum_k enc[m][k]*Wenc[k][n]) * v[n]
// BM=128 rows/block, BN=256 (2-way n-split via blockIdx.x&1), BK=32, 16 k-iters.
// 256 threads = 4 waves: wave (wm,wn) covers rows wm*64..+64, cols wn*128..+128
// => 4 m-frags x 8 n-frags of 16x16x32 bf16 MFMA.
// Software-pipelined: double-buffered LDS, prefetch issued before MFMA phase,
// single __syncthreads per k-iter.
__global__ __launch_bounds__(256)
void score_gemm(const float* __restrict__ enc,
                const short* __restrict__ Bt,   // bf16 bits [512][512] (n-major)
                const float* __restrict__ p,    // [64][512]
                const float* __restrict__ va,   // [512]
                float* __restrict__ score) {    // [131072], pre-zeroed
    __shared__ short Alds[2][128 * 32];   // 2 x 8 KB  [row][k]
    __shared__ short Blds[2][256 * 32];   // 2 x 16 KB [n][k]
    __shared__ float sp[4][64];

    const int tid  = threadIdx.x;
    const int wave = tid >> 6;
    const int lane = tid & 63;
    const int mblk = blockIdx.x >> 1;
    const int n0   = (blockIdx.x & 1) * 256;   // n-split pairs adjacent -> L3 reuse of A
    const int m0   = mblk * 128;

    const int wm = wave >> 1, wn = wave & 1;
    const int lm = lane & 15, lq = lane >> 4;

    f32x4 acc[4][8];
    #pragma unroll
    for (int i = 0; i < 4; ++i)
        #pragma unroll
        for (int j = 0; j < 8; ++j)
            acc[i][j] = (f32x4){0.f, 0.f, 0.f, 0.f};

    // A staging: thread t handles rows (t>>2) and (t>>2)+64, k-chunk (t&3)*8
    const int arow = tid >> 2;
    const int acol = (tid & 3) * 8;
    const float* aptr0 = enc + (size_t)(m0 + arow) * DD + acol;
    const float* aptr1 = aptr0 + (size_t)64 * DD;

    // B staging via global_load_lds: wave w stages rows [w*64, w*64+64),
    // 4 issues x 16 rows; lane l -> row +(l>>2), 16B chunk (l&3)
    const short* bptr = Bt + (size_t)(n0 + wave * 64 + (lane >> 2)) * DD + (lane & 3) * 8;

    // ---- prologue: stage kt=0 into buf 0
    #pragma unroll
    for (int i = 0; i < 4; ++i)
        __builtin_amdgcn_global_load_lds(
            (const __attribute__((address_space(1))) void*)(bptr + (size_t)i * 16 * DD),
            (__attribute__((address_space(3))) void*)(&Blds[0][(wave * 64 + i * 16) * 32]),
            16, 0, 0);
    {
        f32x4 x0 = *(const f32x4*)(aptr0);
        f32x4 x1 = *(const f32x4*)(aptr0 + 4);
        f32x4 y0 = *(const f32x4*)(aptr1);
        f32x4 y1 = *(const f32x4*)(aptr1 + 4);
        int4 px, py;
        px.x = f2bf(x0.x) | (f2bf(x0.y) << 16);
        px.y = f2bf(x0.z) | (f2bf(x0.w) << 16);
        px.z = f2bf(x1.x) | (f2bf(x1.y) << 16);
        px.w = f2bf(x1.z) | (f2bf(x1.w) << 16);
        py.x = f2bf(y0.x) | (f2bf(y0.y) << 16);
        py.y = f2bf(y0.z) | (f2bf(y0.w) << 16);
        py.z = f2bf(y1.x) | (f2bf(y1.y) << 16);
        py.w = f2bf(y1.z) | (f2bf(y1.w) << 16);
        *(int4*)(&Alds[0][arow * 32 + acol]) = px;
        *(int4*)(&Alds[0][(arow + 64) * 32 + acol]) = py;
    }
    __syncthreads();

    for (int kt = 0; kt < 16; ++kt) {
        const int c = kt & 1;
        const bool pf = kt < 15;
        f32x4 x0, x1, y0, y1;
        if (pf) {
            const int kn = (kt + 1) * 32;
            // issue B prefetch (async, direct to LDS)
            #pragma unroll
            for (int i = 0; i < 4; ++i)
                __builtin_amdgcn_global_load_lds(
                    (const __attribute__((address_space(1))) void*)(bptr + (size_t)i * 16 * DD + kn),
                    (__attribute__((address_space(3))) void*)(&Blds[1 - c][(wave * 64 + i * 16) * 32]),
                    16, 0, 0);
            // issue A prefetch into registers
            x0 = *(const f32x4*)(aptr0 + kn);
            x1 = *(const f32x4*)(aptr0 + kn + 4);
            y0 = *(const f32x4*)(aptr1 + kn);
            y1 = *(const f32x4*)(aptr1 + kn + 4);
        }
        // ---- compute from buf c
        bf16x8 af[4];
        #pragma unroll
        for (int mf = 0; mf < 4; ++mf)
            af[mf] = *(const bf16x8*)(&Alds[c][(wm * 64 + mf * 16 + lm) * 32 + lq * 8]);
        #pragma unroll
        for (int nf = 0; nf < 8; ++nf) {
            bf16x8 bfr = *(const bf16x8*)(&Blds[c][(wn * 128 + nf * 16 + lm) * 32 + lq * 8]);
            #pragma unroll
            for (int mf = 0; mf < 4; ++mf)
                acc[mf][nf] = __builtin_amdgcn_mfma_f32_16x16x32_bf16(af[mf], bfr, acc[mf][nf], 0, 0, 0);
        }
        // ---- convert + write A prefetch into the other buffer
        if (pf) {
            int4 px, py;
            px.x = f2bf(x0.x) | (f2bf(x0.y) << 16);
            px.y = f2bf(x0.z) | (f2bf(x0.w) << 16);
            px.z = f2bf(x1.x) | (f2bf(x1.y) << 16);
            px.w = f2bf(x1.z) | (f2bf(x1.w) << 16);
            py.x = f2bf(y0.x) | (f2bf(y0.y) << 16);
            py.y = f2bf(y0.z) | (f2bf(y0.w) << 16);
            py.z = f2bf(y1.x) | (f2bf(y1.y) << 16);
            py.w = f2bf(y1.z) | (f2bf(y1.w) << 16);
            *(int4*)(&Alds[1 - c][arow * 32 + acol]) = px;
            *(int4*)(&Alds[1 - c][(arow + 64) * 32 + acol]) = py;
        }
        __syncthreads();
    }

    // ---- epilogue: tanh + dot with v over this block's n-slice, then atomicAdd
    const int b = m0 >> 11;  // m0 / 2048 (BM=128 never straddles a batch)
    float rowsum[4][4];
    #pragma unroll
    for (int mf = 0; mf < 4; ++mf)
        #pragma unroll
        for (int r = 0; r < 4; ++r) rowsum[mf][r] = 0.f;

    #pragma unroll
    for (int nf = 0; nf < 8; ++nf) {
        int n = n0 + wn * 128 + nf * 16 + lm;
        float pv = p[(size_t)b * DD + n];
        float vv = va[n];
        #pragma unroll
        for (int mf = 0; mf < 4; ++mf)
            #pragma unroll
            for (int r = 0; r < 4; ++r)
                rowsum[mf][r] += fast_tanh(pv + acc[mf][nf][r]) * vv;
    }
    // reduce across the 16 lanes holding the same row
    #pragma unroll
    for (int mf = 0; mf < 4; ++mf)
        #pragma unroll
        for (int r = 0; r < 4; ++r) {
            float s = rowsum[mf][r];
            s += __shfl_xor(s, 1);
            s += __shfl_xor(s, 2);
            s += __shfl_xor(s, 4);
            s += __shfl_xor(s, 8);
            rowsum[mf][r] = s;
        }
    if (lm == 0) {
        #pragma unroll
        for (int mf = 0; mf < 4; ++mf)
            #pragma unroll
            for (int r = 0; r < 4; ++r)
                sp[wave][mf * 16 + lq * 4 + r] = rowsum[mf][r];
    }
    __syncthreads();
    if (tid < 128) {
        int row = tid & 63, half = tid >> 6;
        float v = sp[half * 2][row] + sp[half * 2 + 1][row];
        atomicAdd(&score[(size_t)m0 + half * 64 + row], v);
    }
}

// ---------------------------------------------------------------------------
// Softmax over S per batch; writes alignment (output 1). b_v dropped: softmax
// is shift-invariant, so both outputs are unchanged.
__global__ void softmax_k(const float* __restrict__ score, float* __restrict__ align) {
    __shared__ float red[256];
    int b = blockIdx.x, tid = threadIdx.x;
    const float* s = score + (size_t)b * SS;
    float vals[8];
    float mx = -1e30f;
    #pragma unroll
    for (int i = 0; i < 8; ++i) {
        vals[i] = s[i * 256 + tid];
        mx = fmaxf(mx, vals[i]);
    }
    red[tid] = mx; __syncthreads();
    for (int off = 128; off > 0; off >>= 1) {
        if (tid < off) red[tid] = fmaxf(red[tid], red[tid + off]);
        __syncthreads();
    }
    mx = red[0]; __syncthreads();
    float sum = 0.f;
    #pragma unroll
    for (int i = 0; i < 8; ++i) {
        vals[i] = __expf(vals[i] - mx);
        sum += vals[i];
    }
    red[tid] = sum; __syncthreads();
    for (int off = 128; off > 0; off >>= 1) {
        if (tid < off) red[tid] += red[tid + off];
        __syncthreads();
    }
    float inv = 1.0f / red[0];
    #pragma unroll
    for (int i = 0; i < 8; ++i)
        align[(size_t)b * SS + i * 256 + tid] = vals[i] * inv;
}

// ---------------------------------------------------------------------------
// context[b][d] = sum_s align[b][s] * enc[b][s][d]   (atomic accumulate)
__global__ void context_k(const float* __restrict__ enc, const float* __restrict__ align,
                          float* __restrict__ ctx) {
    int bx = blockIdx.x;           // 64 * 16
    int b = bx >> 4, chunk = bx & 15;
    int tid = threadIdx.x;         // 256 threads, float2 each => 512 cols
    const float2* e2 = (const float2*)(enc + ((size_t)b * SS + chunk * 128) * DD);
    const float* a = align + (size_t)b * SS + chunk * 128;
    float2 acc = {0.f, 0.f};
    #pragma unroll 4
    for (int s = 0; s < 128; ++s) {
        float av = a[s];
        float2 e = e2[(size_t)s * 256 + tid];
        acc.x += av * e.x;
        acc.y += av * e.y;
    }
    atomicAdd(&ctx[(size_t)b * DD + tid * 2], acc.x);
    atomicAdd(&ctx[(size_t)b * DD + tid * 2 + 1], acc.y);
}

// ---------------------------------------------------------------------------
extern "C" void kernel_launch(void* const* d_in, const int* in_sizes, int n_in,
                              void* d_out, int out_size, void* d_ws, size_t ws_size,
                              hipStream_t stream) {
    const float* dec = (const float*)d_in[0];  // [64,1,512]
    const float* enc = (const float*)d_in[1];  // [64,2048,512]
    const float* W   = (const float*)d_in[2];  // [1024,512]
    const float* bt  = (const float*)d_in[3];  // [512]
    const float* va  = (const float*)d_in[4];  // [512,1]

    float* out   = (float*)d_out;
    float* ctx   = out;                 // 32768 floats (output 0)
    float* align = out + BB * DD;       // 131072 floats (output 1)

    char*  ws    = (char*)d_ws;
    short* Bt    = (short*)ws;                                   // 512 KB bf16 W_enc^T
    float* p     = (float*)(ws + 512 * 512 * 2);                 // 128 KB
    float* score = (float*)(ws + 512 * 512 * 2 + BB * DD * 4);   // 512 KB

    hipMemsetAsync(ctx, 0, BB * DD * sizeof(float), stream);
    hipMemsetAsync(score, 0, MM * sizeof(float), stream);
    prep_w<<<64, 256, 0, stream>>>(W, Bt);
    prep_p<<<dim3(BB, 2), 256, 0, stream>>>(dec, W, bt, p);
    score_gemm<<<MM / 64, 256, 0, stream>>>(enc, Bt, p, va, score);
    softmax_k<<<BB, 256, 0, stream>>>(score, align);
    context_k<<<BB * 16, 256, 0, stream>>>(enc, align, ctx);
}

// Round 3
// 537.956 us; speedup vs baseline: 1.1237x; 1.1038x over previous
//
#include <hip/hip_runtime.h>
#include <hip/hip_bf16.h>

// Problem constants
#define BB 64
#define SS 2048
#define DD 512
#define MM (BB * SS)  // 131072 rows

typedef __attribute__((ext_vector_type(8))) short bf16x8;
typedef __attribute__((ext_vector_type(4))) float f32x4;

// fp32 -> bf16 bits, round-to-nearest-even
__device__ __forceinline__ unsigned f2bf(float f) {
    unsigned u = __float_as_uint(f);
    u += 0x7FFFu + ((u >> 16) & 1u);
    return u >> 16;
}

__device__ __forceinline__ float fast_tanh(float x) {
    float ax = fabsf(x);
    float e = __expf(-2.0f * ax);                       // (0,1], never overflows
    float t = (1.0f - e) * __builtin_amdgcn_rcpf(1.0f + e);
    return x < 0.0f ? -t : t;
}

// ---------------------------------------------------------------------------
// Prep 1: Bt[n][k] = bf16(W_t[512+k][n]).  64x64 LDS tile transpose.
__global__ void prep_w(const float* __restrict__ W, short* __restrict__ Bt) {
    __shared__ float tile[64][65];
    int kt = blockIdx.x >> 3;      // 8 x 8 tiles
    int nt = blockIdx.x & 7;
    int t = threadIdx.x;
    int c = t & 63;
    int rbase = (t >> 6) * 16;
    #pragma unroll
    for (int i = 0; i < 16; ++i) {
        int r = rbase + i;
        tile[r][c] = W[(size_t)(512 + kt * 64 + r) * DD + nt * 64 + c];
    }
    __syncthreads();
    #pragma unroll
    for (int i = 0; i < 16; ++i) {
        int r = rbase + i;
        Bt[(size_t)(nt * 64 + r) * DD + kt * 64 + c] = (short)f2bf(tile[c][r]);
    }
}

// Prep 2: p[b][d] = sum_e dec[b][e] * W_t[e][d] + b_t[d]   (fp32, exact)
__global__ void prep_p(const float* __restrict__ dec, const float* __restrict__ W,
                       const float* __restrict__ bt, float* __restrict__ p) {
    int b = blockIdx.x;
    int d = blockIdx.y * 256 + threadIdx.x;
    float acc = bt[d];
    const float* dv = dec + (size_t)b * DD;
    #pragma unroll 8
    for (int e = 0; e < DD; ++e)
        acc += dv[e] * W[(size_t)e * DD + d];
    p[(size_t)b * DD + d] = acc;
}

// ---------------------------------------------------------------------------
// Score GEMM, 4-way n-split:
//   score[m] += sum_{n in slice} tanh(p[b][n] + sum_k enc[m][k]*Wenc[k][n]) * v[n]
// BM=128, BN=128, BK=32, 16 k-iters. 256 threads = 4 waves, wave tile 64x64:
// 4 m-frags x 4 n-frags of 16x16x32 bf16 MFMA -> acc = 64 regs/thread.
// Register budget (the round-2 lesson): acc 64 + ~160 arch VGPR stays under
// 256 total -> 2-3 waves/SIMD so inter-block overlap hides latency.
__global__ __launch_bounds__(256, 2)
void score_gemm(const float* __restrict__ enc,
                const short* __restrict__ Bt,   // bf16 bits [512][512] (n-major)
                const float* __restrict__ p,    // [64][512]
                const float* __restrict__ va,   // [512]
                float* __restrict__ score) {    // [131072], pre-zeroed
    __shared__ short Alds[2][128 * 32];   // 2 x 8 KB  [row][k]
    __shared__ short Blds[2][128 * 32];   // 2 x 8 KB  [n][k]
    __shared__ float sp[4][64];

    const int tid  = threadIdx.x;
    const int wave = tid >> 6;
    const int lane = tid & 63;
    const int mblk = blockIdx.x >> 2;
    const int n0   = (blockIdx.x & 3) * 128;   // n-split adjacent -> L3 reuse of A
    const int m0   = mblk * 128;

    const int wm = wave >> 1, wn = wave & 1;
    const int lm = lane & 15, lq = lane >> 4;

    f32x4 acc[4][4];
    #pragma unroll
    for (int i = 0; i < 4; ++i)
        #pragma unroll
        for (int j = 0; j < 4; ++j)
            acc[i][j] = (f32x4){0.f, 0.f, 0.f, 0.f};

    // A staging: thread t -> row t>>1 (0..127), 16 floats at col (t&1)*16
    const int arow = tid >> 1;
    const int acol = (tid & 1) * 16;
    const float* aptr = enc + (size_t)(m0 + arow) * DD + acol;

    // B staging via global_load_lds: wave w stages n-rows [w*32, w*32+32),
    // 2 issues x 16 rows; lane l -> row +(l>>2), 16B chunk (l&3)
    const short* bptr = Bt + (size_t)(n0 + wave * 32 + (lane >> 2)) * DD + (lane & 3) * 8;

    // ---- prologue: stage kt=0 into buf 0
    #pragma unroll
    for (int i = 0; i < 2; ++i)
        __builtin_amdgcn_global_load_lds(
            (const __attribute__((address_space(1))) void*)(bptr + (size_t)i * 16 * DD),
            (__attribute__((address_space(3))) void*)(&Blds[0][(wave * 32 + i * 16) * 32]),
            16, 0, 0);
    {
        f32x4 x0 = *(const f32x4*)(aptr);
        f32x4 x1 = *(const f32x4*)(aptr + 4);
        f32x4 x2 = *(const f32x4*)(aptr + 8);
        f32x4 x3 = *(const f32x4*)(aptr + 12);
        int4 p0, p1;
        p0.x = f2bf(x0.x) | (f2bf(x0.y) << 16);
        p0.y = f2bf(x0.z) | (f2bf(x0.w) << 16);
        p0.z = f2bf(x1.x) | (f2bf(x1.y) << 16);
        p0.w = f2bf(x1.z) | (f2bf(x1.w) << 16);
        p1.x = f2bf(x2.x) | (f2bf(x2.y) << 16);
        p1.y = f2bf(x2.z) | (f2bf(x2.w) << 16);
        p1.z = f2bf(x3.x) | (f2bf(x3.y) << 16);
        p1.w = f2bf(x3.z) | (f2bf(x3.w) << 16);
        *(int4*)(&Alds[0][arow * 32 + acol]) = p0;
        *(int4*)(&Alds[0][arow * 32 + acol + 8]) = p1;
    }
    __syncthreads();

    for (int kt = 0; kt < 16; ++kt) {
        const int c = kt & 1;
        const bool pf = kt < 15;
        f32x4 x0, x1, x2, x3;
        if (pf) {
            const int kn = (kt + 1) * 32;
            // issue B prefetch (async, direct to LDS)
            #pragma unroll
            for (int i = 0; i < 2; ++i)
                __builtin_amdgcn_global_load_lds(
                    (const __attribute__((address_space(1))) void*)(bptr + (size_t)i * 16 * DD + kn),
                    (__attribute__((address_space(3))) void*)(&Blds[1 - c][(wave * 32 + i * 16) * 32]),
                    16, 0, 0);
            // issue A prefetch into registers
            x0 = *(const f32x4*)(aptr + kn);
            x1 = *(const f32x4*)(aptr + kn + 4);
            x2 = *(const f32x4*)(aptr + kn + 8);
            x3 = *(const f32x4*)(aptr + kn + 12);
        }
        // ---- compute from buf c
        bf16x8 af[4];
        #pragma unroll
        for (int mf = 0; mf < 4; ++mf)
            af[mf] = *(const bf16x8*)(&Alds[c][(wm * 64 + mf * 16 + lm) * 32 + lq * 8]);
        #pragma unroll
        for (int nf = 0; nf < 4; ++nf) {
            bf16x8 bfr = *(const bf16x8*)(&Blds[c][(wn * 64 + nf * 16 + lm) * 32 + lq * 8]);
            #pragma unroll
            for (int mf = 0; mf < 4; ++mf)
                acc[mf][nf] = __builtin_amdgcn_mfma_f32_16x16x32_bf16(af[mf], bfr, acc[mf][nf], 0, 0, 0);
        }
        // ---- convert + write A prefetch into the other buffer
        if (pf) {
            int4 p0, p1;
            p0.x = f2bf(x0.x) | (f2bf(x0.y) << 16);
            p0.y = f2bf(x0.z) | (f2bf(x0.w) << 16);
            p0.z = f2bf(x1.x) | (f2bf(x1.y) << 16);
            p0.w = f2bf(x1.z) | (f2bf(x1.w) << 16);
            p1.x = f2bf(x2.x) | (f2bf(x2.y) << 16);
            p1.y = f2bf(x2.z) | (f2bf(x2.w) << 16);
            p1.z = f2bf(x3.x) | (f2bf(x3.y) << 16);
            p1.w = f2bf(x3.z) | (f2bf(x3.w) << 16);
            *(int4*)(&Alds[1 - c][arow * 32 + acol]) = p0;
            *(int4*)(&Alds[1 - c][arow * 32 + acol + 8]) = p1;
        }
        __syncthreads();
    }

    // ---- epilogue: tanh + dot with v over this block's n-slice, then atomicAdd
    const int b = m0 >> 11;  // m0 / 2048 (BM=128 never straddles a batch)
    float rowsum[4][4];
    #pragma unroll
    for (int mf = 0; mf < 4; ++mf)
        #pragma unroll
        for (int r = 0; r < 4; ++r) rowsum[mf][r] = 0.f;

    #pragma unroll
    for (int nf = 0; nf < 4; ++nf) {
        int n = n0 + wn * 64 + nf * 16 + lm;
        float pv = p[(size_t)b * DD + n];
        float vv = va[n];
        #pragma unroll
        for (int mf = 0; mf < 4; ++mf)
            #pragma unroll
            for (int r = 0; r < 4; ++r)
                rowsum[mf][r] += fast_tanh(pv + acc[mf][nf][r]) * vv;
    }
    // reduce across the 16 lanes holding the same row
    #pragma unroll
    for (int mf = 0; mf < 4; ++mf)
        #pragma unroll
        for (int r = 0; r < 4; ++r) {
            float s = rowsum[mf][r];
            s += __shfl_xor(s, 1);
            s += __shfl_xor(s, 2);
            s += __shfl_xor(s, 4);
            s += __shfl_xor(s, 8);
            rowsum[mf][r] = s;
        }
    if (lm == 0) {
        #pragma unroll
        for (int mf = 0; mf < 4; ++mf)
            #pragma unroll
            for (int r = 0; r < 4; ++r)
                sp[wave][mf * 16 + lq * 4 + r] = rowsum[mf][r];
    }
    __syncthreads();
    if (tid < 128) {
        int row = tid & 63, half = tid >> 6;   // half = wm
        float v = sp[half * 2][row] + sp[half * 2 + 1][row];
        atomicAdd(&score[(size_t)m0 + half * 64 + row], v);
    }
}

// ---------------------------------------------------------------------------
// Softmax over S per batch; writes alignment (output 1). b_v dropped: softmax
// is shift-invariant, so both outputs are unchanged.
__global__ void softmax_k(const float* __restrict__ score, float* __restrict__ align) {
    __shared__ float red[256];
    int b = blockIdx.x, tid = threadIdx.x;
    const float* s = score + (size_t)b * SS;
    float vals[8];
    float mx = -1e30f;
    #pragma unroll
    for (int i = 0; i < 8; ++i) {
        vals[i] = s[i * 256 + tid];
        mx = fmaxf(mx, vals[i]);
    }
    red[tid] = mx; __syncthreads();
    for (int off = 128; off > 0; off >>= 1) {
        if (tid < off) red[tid] = fmaxf(red[tid], red[tid + off]);
        __syncthreads();
    }
    mx = red[0]; __syncthreads();
    float sum = 0.f;
    #pragma unroll
    for (int i = 0; i < 8; ++i) {
        vals[i] = __expf(vals[i] - mx);
        sum += vals[i];
    }
    red[tid] = sum; __syncthreads();
    for (int off = 128; off > 0; off >>= 1) {
        if (tid < off) red[tid] += red[tid + off];
        __syncthreads();
    }
    float inv = 1.0f / red[0];
    #pragma unroll
    for (int i = 0; i < 8; ++i)
        align[(size_t)b * SS + i * 256 + tid] = vals[i] * inv;
}

// ---------------------------------------------------------------------------
// context[b][d] = sum_s align[b][s] * enc[b][s][d]   (atomic accumulate)
__global__ void context_k(const float* __restrict__ enc, const float* __restrict__ align,
                          float* __restrict__ ctx) {
    int bx = blockIdx.x;           // 64 * 16
    int b = bx >> 4, chunk = bx & 15;
    int tid = threadIdx.x;         // 256 threads, float2 each => 512 cols
    const float2* e2 = (const float2*)(enc + ((size_t)b * SS + chunk * 128) * DD);
    const float* a = align + (size_t)b * SS + chunk * 128;
    float2 acc = {0.f, 0.f};
    #pragma unroll 4
    for (int s = 0; s < 128; ++s) {
        float av = a[s];
        float2 e = e2[(size_t)s * 256 + tid];
        acc.x += av * e.x;
        acc.y += av * e.y;
    }
    atomicAdd(&ctx[(size_t)b * DD + tid * 2], acc.x);
    atomicAdd(&ctx[(size_t)b * DD + tid * 2 + 1], acc.y);
}

// ---------------------------------------------------------------------------
extern "C" void kernel_launch(void* const* d_in, const int* in_sizes, int n_in,
                              void* d_out, int out_size, void* d_ws, size_t ws_size,
                              hipStream_t stream) {
    const float* dec = (const float*)d_in[0];  // [64,1,512]
    const float* enc = (const float*)d_in[1];  // [64,2048,512]
    const float* W   = (const float*)d_in[2];  // [1024,512]
    const float* bt  = (const float*)d_in[3];  // [512]
    const float* va  = (const float*)d_in[4];  // [512,1]

    float* out   = (float*)d_out;
    float* ctx   = out;                 // 32768 floats (output 0)
    float* align = out + BB * DD;       // 131072 floats (output 1)

    char*  ws    = (char*)d_ws;
    short* Bt    = (short*)ws;                                   // 512 KB bf16 W_enc^T
    float* p     = (float*)(ws + 512 * 512 * 2);                 // 128 KB
    float* score = (float*)(ws + 512 * 512 * 2 + BB * DD * 4);   // 512 KB

    hipMemsetAsync(ctx, 0, BB * DD * sizeof(float), stream);
    hipMemsetAsync(score, 0, MM * sizeof(float), stream);
    prep_w<<<64, 256, 0, stream>>>(W, Bt);
    prep_p<<<dim3(BB, 2), 256, 0, stream>>>(dec, W, bt, p);
    score_gemm<<<MM / 32, 256, 0, stream>>>(enc, Bt, p, va, score);  // 4096 blocks
    softmax_k<<<BB, 256, 0, stream>>>(score, align);
    context_k<<<BB * 16, 256, 0, stream>>>(enc, align, ctx);
}